// Round 7
// baseline (4377.008 us; speedup 1.0000x reference)
//
#include <hip/hip_runtime.h>
#include <cstdint>

// LSTM fused kernel for MI355X — round 7.
// 64 blocks (1/batch) x 1024 threads. Wave w self-contains units 16w..16w+15:
// lane l = g*16 + j handles gate g of unit 16w+j. Gate exchange = 3 intra-wave
// shfl_xor (16/32/48) -> ONE barrier/step, ZERO LDS in the loop. h-production
// spread across all 16 waves (lanes 0-15 each). s_load issue / x-dot overlap /
// tied s_waitcnt split so K$ latency hides behind x-dots. x records prefetched
// into VGPRs one step ahead. Replay-proven envelope kept from r6: identity
// h slots, full-dword distinct stores only, launch_bounds(1024,4), builtin
// dot4, no waves_per_eu, no pin asm.

#define B_  64
#define T_  2048
#define I_  32
#define H_  256
#define G4  1024
#define O_  32

typedef int v16i __attribute__((ext_vector_type(16)));
typedef _Float16 h2_t __attribute__((ext_vector_type(2)));

#if __has_builtin(__builtin_amdgcn_sdot4)
__device__ __forceinline__ int dot4(int a, int b, int c) {
    return __builtin_amdgcn_sdot4(a, b, c, false);
}
#else
__device__ __forceinline__ int dot4(int a, int b, int c) {
    c += (int)(int8_t)(a)        * (int)(int8_t)(b);
    c += (int)(int8_t)(a >> 8)   * (int)(int8_t)(b >> 8);
    c += (int)(int8_t)(a >> 16)  * (int)(int8_t)(b >> 16);
    c += (int)(int8_t)(a >> 24)  * (int)(int8_t)(b >> 24);
    return c;
}
#endif

__device__ __forceinline__ float fdot2h(h2_t a, h2_t b, float c) {
#if __has_builtin(__builtin_amdgcn_fdot2)
    return __builtin_amdgcn_fdot2(a, b, c, false);
#else
    return c + (float)a[0] * (float)b[0] + (float)a[1] * (float)b[1];
#endif
}

// ---------------- ws layout ----------------
// qwhh : uint32 [64][1024]  @0        (262144 B)   dword d of row r at [d][col(r)]
// qwih : uint32 [8][1024]   @262144   (32768 B)
// s1/s2/bias (permuted by col): float [1024] @294912/299008/303104
// xq   : [B*T] 72-B records @307200   (9437184 B)  [8dw hi][8dw lo][f32 scale]
// hbuf : [B] x 2049 x 512 B @9744384  (67141632 B)
//        record: [256 int8 h][16 f32 group scales (64B)][pad 192B]
#define QWHH_OFF 0u
#define QWIH_OFF 262144u
#define S1_OFF   294912u
#define S2_OFF   299008u
#define BIAS_OFF 303104u
#define XQ_OFF   307200u
#define HBUF_OFF 9744384u
#define XREC  72
#define HREC  512
#define HSLOTS 2049

__device__ __forceinline__ uint32_t pack_q(int q0, int q1, int q2, int q3) {
    return  ((uint32_t)(uint8_t)(int8_t)q0)
          | (((uint32_t)(uint8_t)(int8_t)q1) << 8)
          | (((uint32_t)(uint8_t)(int8_t)q2) << 16)
          | (((uint32_t)(uint8_t)(int8_t)q3) << 24);
}
__device__ __forceinline__ int clamp127(int v) {
    return v < -127 ? -127 : (v > 127 ? 127 : v);
}

// column mapping: row r: unit u=r&255, gate g=r>>8
// col(r) = (u>>4)*64 + g*16 + (u&15)

// -------- prep: quantize weights into permuted columns --------
__global__ __launch_bounds__(64) void prep_w(
    const float* __restrict__ Whh, const float* __restrict__ Wih,
    const float* __restrict__ bih, const float* __restrict__ bhh,
    uint32_t* __restrict__ qwhh, uint32_t* __restrict__ qwih,
    float* __restrict__ s1, float* __restrict__ s2, float* __restrict__ bias)
{
    const int r = blockIdx.x;           // gate row 0..1023
    const int l = threadIdx.x;          // 0..63
    const int u = r & 255, g = r >> 8;
    const int col = ((u >> 4) << 6) + (g << 4) + (u & 15);

    const float4 wv = ((const float4*)(Whh + r * H_))[l];
    float m = fmaxf(fmaxf(fabsf(wv.x), fabsf(wv.y)), fmaxf(fabsf(wv.z), fabsf(wv.w)));
    #pragma unroll
    for (int s = 1; s < 64; s <<= 1) m = fmaxf(m, __shfl_xor(m, s, 64));
    const float S1 = fmaxf(m, 1e-20f) / 127.f;

    float xm = (l < I_) ? fabsf(Wih[r * I_ + l]) : 0.f;
    #pragma unroll
    for (int s = 1; s < 64; s <<= 1) xm = fmaxf(xm, __shfl_xor(xm, s, 64));
    const float S2 = fmaxf(xm, 1e-20f) / 127.f;

    {
        const float r1 = 1.f / S1;
        qwhh[l * G4 + col] = pack_q(
            clamp127((int)rintf(wv.x * r1)), clamp127((int)rintf(wv.y * r1)),
            clamp127((int)rintf(wv.z * r1)), clamp127((int)rintf(wv.w * r1)));
    }
    if (l < 8) {
        const float4 xw = ((const float4*)(Wih + r * I_))[l];
        const float r2 = 1.f / S2;
        qwih[l * G4 + col] = pack_q(
            clamp127((int)rintf(xw.x * r2)), clamp127((int)rintf(xw.y * r2)),
            clamp127((int)rintf(xw.z * r2)), clamp127((int)rintf(xw.w * r2)));
    }
    if (l == 0) { s1[col] = S1; s2[col] = S2; bias[col] = bih[r] + bhh[r]; }
}

// -------- prep: quantize x into 72-B records (hi/lo int8 + f32 scale) ------
__global__ __launch_bounds__(256) void prep_x(
    const float* __restrict__ x, char* __restrict__ xq)
{
    __shared__ float xb[64 * 32];
    const int base = blockIdx.x * 64 * 32;
    for (int i = threadIdx.x; i < 2048; i += 256) xb[i] = x[base + i];
    __syncthreads();
    const int t = threadIdx.x;
    if (t < 64) {
        float m = 0.f;
        for (int k = 0; k < 32; k++) m = fmaxf(m, fabsf(xb[t * 32 + k]));
        const float S = fmaxf(m, 1e-20f) / 127.f;
        const float rS = 1.f / S;
        const int row = blockIdx.x * 64 + t;
        uint32_t* rec = (uint32_t*)(xq + (size_t)row * XREC);
        for (int jj = 0; jj < 8; jj++) {
            int qa[4], qb[4];
            for (int e = 0; e < 4; e++) {
                float v = xb[t * 32 + jj * 4 + e] * rS;
                int a = clamp127((int)rintf(v));
                int b = clamp127((int)rintf((v - (float)a) * 127.f));
                qa[e] = a; qb[e] = b;
            }
            rec[jj]     = pack_q(qa[0], qa[1], qa[2], qa[3]);
            rec[8 + jj] = pack_q(qb[0], qb[1], qb[2], qb[3]);
        }
        ((float*)rec)[16] = S;
    }
}

#define GRP4(GACC, HV, D0, SC) { int a_ = 0; \
    a_ = dot4((int)w[(D0)+0], HV[((D0)+0) & 15], a_); \
    a_ = dot4((int)w[(D0)+1], HV[((D0)+1) & 15], a_); \
    a_ = dot4((int)w[(D0)+2], HV[((D0)+2) & 15], a_); \
    a_ = dot4((int)w[(D0)+3], HV[((D0)+3) & 15], a_); \
    GACC = fmaf((float)a_, (SC), GACC); }

// -------- main: full LSTM, one block per batch, 1024 threads ---------------
__global__ __launch_bounds__(1024, 4) void lstm_main(
    const uint32_t* __restrict__ qwhh, const uint32_t* __restrict__ qwih,
    const float* __restrict__ s1v, const float* __restrict__ s2v,
    const float* __restrict__ biasv, const char* __restrict__ xq,
    char* __restrict__ hbuf)
{
    const int b   = blockIdx.x;
    const int tid = threadIdx.x;
    const int w_  = tid >> 6, l = tid & 63;
    const int g   = l >> 4;                 // 0=i 1=f 2=g 3=o

    uint32_t w[64];
    #pragma unroll
    for (int d = 0; d < 64; d++) w[d] = qwhh[d * G4 + tid];
    uint32_t wx[8];
    #pragma unroll
    for (int k = 0; k < 8; k++) wx[k] = qwih[k * G4 + tid];

    const float S1 = s1v[tid], S2 = s2v[tid], biasr = biasv[tid];
    const float sA = (g == 2) ? 2.f : 1.f;  // g-gate: tanh = 2*sig(2x)-1
    const float mA = sA;
    const float cA = (g == 2) ? -1.f : 0.f;

    char* hb = hbuf + (size_t)b * ((size_t)HSLOTS * HREC);
    const char* xbp = xq + (size_t)b * T_ * XREC;
    if (tid < 80) ((uint32_t*)hb)[tid] = 0u;  // slot 0: zero h + zero scales
    float c_state = 0.f;                      // valid for lanes l<16

    // preload x(0) record into VGPRs (wave-uniform address; per-lane copies)
    uint4 x0v, x1v, x2v, x3v; float Sx;
    {
        const uint4* xr = (const uint4*)xbp;
        x0v = xr[0]; x1v = xr[1]; x2v = xr[2]; x3v = xr[3];
        Sx = *(const float*)(xbp + 64);
    }
    __syncthreads();

    for (int t = 0; t < T_; t++) {
        const char* hrec = hb + (size_t)t * HREC;
        v16i h0, h1, h2, h3, scv;
        // issue the 5 broadcast s_loads, NO wait yet
        asm volatile(
            "s_load_dwordx16 %0, %5, 0x0\n\t"
            "s_load_dwordx16 %1, %5, 0x40\n\t"
            "s_load_dwordx16 %2, %5, 0x80\n\t"
            "s_load_dwordx16 %3, %5, 0xc0\n\t"
            "s_load_dwordx16 %4, %5, 0x100"
            : "=&s"(h0), "=&s"(h1), "=&s"(h2), "=&s"(h3), "=&s"(scv)
            : "s"(hrec)
            : "memory");

        // x contribution while h-record is in flight
        int aA = 0, aL = 0;
        aA = dot4((int)wx[0], (int)x0v.x, aA); aA = dot4((int)wx[1], (int)x0v.y, aA);
        aA = dot4((int)wx[2], (int)x0v.z, aA); aA = dot4((int)wx[3], (int)x0v.w, aA);
        aA = dot4((int)wx[4], (int)x1v.x, aA); aA = dot4((int)wx[5], (int)x1v.y, aA);
        aA = dot4((int)wx[6], (int)x1v.z, aA); aA = dot4((int)wx[7], (int)x1v.w, aA);
        aL = dot4((int)wx[0], (int)x2v.x, aL); aL = dot4((int)wx[1], (int)x2v.y, aL);
        aL = dot4((int)wx[2], (int)x2v.z, aL); aL = dot4((int)wx[3], (int)x2v.w, aL);
        aL = dot4((int)wx[4], (int)x3v.x, aL); aL = dot4((int)wx[5], (int)x3v.y, aL);
        aL = dot4((int)wx[6], (int)x3v.z, aL); aL = dot4((int)wx[7], (int)x3v.w, aL);
        const float xcontrib =
            ((float)aA + (float)aL * (1.f / 127.f)) * (S2 * Sx) + biasr;

        // wait for h data; tie so consumers can't be scheduled above the wait
        asm volatile("s_waitcnt lgkmcnt(0)"
                     : "+s"(h0), "+s"(h1), "+s"(h2), "+s"(h3), "+s"(scv));

        // recurrent dots: 16 scale groups of 16 units
        float gacc = 0.f;
        GRP4(gacc, h0,  0, __int_as_float(scv[0]));
        GRP4(gacc, h0,  4, __int_as_float(scv[1]));
        GRP4(gacc, h0,  8, __int_as_float(scv[2]));
        GRP4(gacc, h0, 12, __int_as_float(scv[3]));
        GRP4(gacc, h1, 16, __int_as_float(scv[4]));
        GRP4(gacc, h1, 20, __int_as_float(scv[5]));
        GRP4(gacc, h1, 24, __int_as_float(scv[6]));
        GRP4(gacc, h1, 28, __int_as_float(scv[7]));
        GRP4(gacc, h2, 32, __int_as_float(scv[8]));
        GRP4(gacc, h2, 36, __int_as_float(scv[9]));
        GRP4(gacc, h2, 40, __int_as_float(scv[10]));
        GRP4(gacc, h2, 44, __int_as_float(scv[11]));
        GRP4(gacc, h3, 48, __int_as_float(scv[12]));
        GRP4(gacc, h3, 52, __int_as_float(scv[13]));
        GRP4(gacc, h3, 56, __int_as_float(scv[14]));
        GRP4(gacc, h3, 60, __int_as_float(scv[15]));

        const float gate = gacc * S1 + xcontrib;
        const float y = fmaf(1.f / (1.f + __expf(-sA * gate)), mA, cA);

        // intra-wave gate exchange: lane l<16 (i) pulls f,g,o from l+16/32/48
        const float yf = __shfl_xor(y, 16, 64);
        const float yg = __shfl_xor(y, 32, 64);
        const float yo = __shfl_xor(y, 48, 64);

        // prefetch next x record (WAR on x*v: ordered after the dots above)
        {
            const uint4* xr = (const uint4*)(xbp + (size_t)(t + 1) * XREC);
            x0v = xr[0]; x1v = xr[1]; x2v = xr[2]; x3v = xr[3];
            Sx = *(const float*)(xbp + (size_t)(t + 1) * XREC + 64);
        }

        char* hw = hb + (size_t)(t + 1) * HREC;
        if (l < 16) {                       // every wave: units 16w..16w+15
            c_state = yf * c_state + y * yg;                 // f*c + i*g
            const float tc = 2.f / (1.f + __expf(-2.f * c_state)) - 1.f;
            const float hval = yo * tc;

            // per-16-unit (wave) max + int8 quantize
            float m = fabsf(hval);
            m = fmaxf(m, __shfl_xor(m, 1, 64));
            m = fmaxf(m, __shfl_xor(m, 2, 64));
            m = fmaxf(m, __shfl_xor(m, 4, 64));
            m = fmaxf(m, __shfl_xor(m, 8, 64));
            m = fmaxf(m, 1e-12f);
            const int q = clamp127((int)rintf(hval * (127.f / m)));

            // pack int8 x4 -> full-dword stores at lanes 0,4,8,12
            uint32_t q8 = (uint32_t)q & 0xffu;
            uint32_t p = q8 | (((uint32_t)__shfl_xor((int)q8, 1, 64)) << 8);
            p = p | (((uint32_t)__shfl_xor((int)p, 2, 64)) << 16);
            if ((l & 3) == 0) *(uint32_t*)(hw + 16 * w_ + l) = p;
            if (l == 0) ((float*)(hw + 256))[w_] = m * (1.f / 127.f);
        }
        __syncthreads();   // stores drained (vmcnt) ; next step's s_load safe
    }
}

// -------- post: fc GEMM, dequantizing int8 h records (16 scale groups) -----
__global__ __launch_bounds__(256) void fc_kernel(
    const char* __restrict__ hbuf, const float* __restrict__ fcw,
    const float* __restrict__ fcb, float* __restrict__ out)
{
    __shared__ uint32_t hlds[64 * 128];      // 32 KB: 64 timesteps of f16-pair h
    __shared__ uint32_t wlds[32 * 32 * 4];   // 16 KB: [chunk][o][e] f16 pairs
    const int b  = blockIdx.x >> 5;
    const int t0 = (blockIdx.x & 31) * 64;
    const char* hb = hbuf + (size_t)b * ((size_t)HSLOTS * HREC);

    // dequant: thread -> (record, 64-unit chunk); 16-unit scale groups
    {
        const int rec = threadIdx.x >> 2, g4 = threadIdx.x & 3;
        const char* rp = hb + (size_t)(t0 + rec + 1) * HREC;
        #pragma unroll
        for (int qq = 0; qq < 4; qq++) {
            const float sc = *(const float*)(rp + 256 + 4 * (g4 * 4 + qq));
            const uint4 d = *(const uint4*)(rp + 64 * g4 + 16 * qq);
            uint32_t vals[4] = {d.x, d.y, d.z, d.w};
            #pragma unroll
            for (int e = 0; e < 4; e++) {
                const uint32_t v = vals[e];
                union { h2_t h; uint32_t u; } p0, p1;
                p0.h[0] = (_Float16)((float)(int)(int8_t)(v)       * sc);
                p0.h[1] = (_Float16)((float)(int)(int8_t)(v >> 8)  * sc);
                p1.h[0] = (_Float16)((float)(int)(int8_t)(v >> 16) * sc);
                p1.h[1] = (_Float16)((float)(int)(int8_t)(v >> 24) * sc);
                const int di = rec * 128 + g4 * 32 + qq * 8 + e * 2;
                hlds[di]     = p0.u;
                hlds[di + 1] = p1.u;
            }
        }
    }
    for (int i = threadIdx.x; i < 4096; i += 256) {
        const int o = i >> 7, kp = i & 127;
        union { h2_t h; uint32_t u; } cv;
        cv.h[0] = (_Float16)fcw[o * 256 + 2 * kp];
        cv.h[1] = (_Float16)fcw[o * 256 + 2 * kp + 1];
        wlds[((kp >> 2) * 32 + o) * 4 + (kp & 3)] = cv.u;
    }
    __syncthreads();

    const int o = threadIdx.x & 31, rg = threadIdx.x >> 5;
    const float bv = fcb[o];
    float acc[8];
    #pragma unroll
    for (int rr = 0; rr < 8; rr++) acc[rr] = bv;

    for (int ch = 0; ch < 32; ch++) {
        const uint4 wv = *(const uint4*)(wlds + (ch * 32 + o) * 4);
        union { uint32_t u; h2_t h; } w0, w1, w2, w3;
        w0.u = wv.x; w1.u = wv.y; w2.u = wv.z; w3.u = wv.w;
        #pragma unroll
        for (int rr = 0; rr < 8; rr++) {
            const int rowi = rg * 8 + rr;
            const uint4 hv = *(const uint4*)(hlds + rowi * 128 + ch * 4);
            union { uint32_t u; h2_t h; } y0, y1, y2, y3;
            y0.u = hv.x; y1.u = hv.y; y2.u = hv.z; y3.u = hv.w;
            float a = acc[rr];
            a = fdot2h(w0.h, y0.h, a);
            a = fdot2h(w1.h, y1.h, a);
            a = fdot2h(w2.h, y2.h, a);
            a = fdot2h(w3.h, y3.h, a);
            acc[rr] = a;
        }
    }
    #pragma unroll
    for (int rr = 0; rr < 8; rr++)
        out[((size_t)b * T_ + t0 + rg * 8 + rr) * O_ + o] = acc[rr];
}

extern "C" void kernel_launch(void* const* d_in, const int* in_sizes, int n_in,
                              void* d_out, int out_size, void* d_ws, size_t ws_size,
                              hipStream_t stream) {
    const float* x    = (const float*)d_in[0];
    const float* Wih  = (const float*)d_in[1];
    const float* Whh  = (const float*)d_in[2];
    const float* bih  = (const float*)d_in[3];
    const float* bhh  = (const float*)d_in[4];
    const float* fcw  = (const float*)d_in[5];
    const float* fcb  = (const float*)d_in[6];
    float* out = (float*)d_out;

    char* ws = (char*)d_ws;
    uint32_t* qwhh = (uint32_t*)(ws + QWHH_OFF);
    uint32_t* qwih = (uint32_t*)(ws + QWIH_OFF);
    float*    s1   = (float*)(ws + S1_OFF);
    float*    s2   = (float*)(ws + S2_OFF);
    float*    bias = (float*)(ws + BIAS_OFF);
    char*     xq   = ws + XQ_OFF;
    char*     hbuf = ws + HBUF_OFF;

    prep_w<<<G4, 64, 0, stream>>>(Whh, Wih, bih, bhh, qwhh, qwih, s1, s2, bias);
    prep_x<<<(B_ * T_) / 64, 256, 0, stream>>>(x, xq);
    lstm_main<<<B_, 1024, 0, stream>>>(qwhh, qwih, s1, s2, bias, xq, hbuf);
    fc_kernel<<<(B_ * T_) / 64, 256, 0, stream>>>(hbuf, fcw, fcb, out);
}